// Round 2
// baseline (774.310 us; speedup 1.0000x reference)
//
#include <hip/hip_runtime.h>
#include <hip/hip_bf16.h>
#include <cstdint>
#include <cstddef>

// Problem constants (Qwen2: B=2,S=4096,H=3584,NH=28,NKV=4,D=128)
#define SS 4096
#define HH 3584
#define NHQ 28
#define NKVH 4
#define DD 128
#define MM 8192                 // B*S
#define NN 4608                 // (NH+2*NKV)*D
#define KK 3584
#define QOFF 0
#define KOFF 29360128ULL        // B*NH*S*D
#define VOFF 33554432ULL        // KOFF + B*NKV*S*D

// GEMM tiling: 256x128 tile, BK=64, 8 waves (512 thr), 3-stage pipeline
#define BM 256
#define BN 128
#define BK 64
#define NKT 56                  // KK/BK
#define NBN2 36                 // NN/BN
#define GRID_GEMM 1152          // (MM/BM)*(NN/BN) = 32*36, %8==0 -> bijective XCD swizzle

// prep block ranges
#define NB_CVT 7168             // MM*KK/16/256
#define NB_TQ 3136              // (3584/64)*(3584/64)
#define NB_TK 448               // (512/64)*(3584/64)
#define NB_PREP (NB_CVT + NB_TQ + 2 * NB_TK)

typedef __bf16 bf16;
typedef bf16  bf16x8  __attribute__((ext_vector_type(8)));
typedef float floatx4 __attribute__((ext_vector_type(4)));

// ------------------------------------------------------------- fused prep ---
__global__ __launch_bounds__(256) void prep(
    const float* __restrict__ hs, const float* __restrict__ Wq,
    const float* __restrict__ Wk, const float* __restrict__ Wv,
    bf16* __restrict__ Abf, bf16* __restrict__ Bt) {

    int blk = blockIdx.x;
    if (blk < NB_CVT) {
        size_t i = (size_t)blk * 256 + threadIdx.x;      // 16 floats per thread
        const float4* s = (const float4*)hs;
        float4 a = s[4 * i], b = s[4 * i + 1], c = s[4 * i + 2], d = s[4 * i + 3];
        bf16x8 o0, o1;
        o0[0] = (bf16)a.x; o0[1] = (bf16)a.y; o0[2] = (bf16)a.z; o0[3] = (bf16)a.w;
        o0[4] = (bf16)b.x; o0[5] = (bf16)b.y; o0[6] = (bf16)b.z; o0[7] = (bf16)b.w;
        o1[0] = (bf16)c.x; o1[1] = (bf16)c.y; o1[2] = (bf16)c.z; o1[3] = (bf16)c.w;
        o1[4] = (bf16)d.x; o1[5] = (bf16)d.y; o1[6] = (bf16)d.z; o1[7] = (bf16)d.w;
        *(bf16x8*)(Abf + i * 16)     = o0;
        *(bf16x8*)(Abf + i * 16 + 8) = o1;
        return;
    }
    // ---- transpose part: 64x64 fp32 tile -> Bt (n,k) bf16 ----
    const float* W; int ncols, row_off, nb, kb;
    int t = blk - NB_CVT;
    if (t < NB_TQ)            { W = Wq; ncols = 3584; row_off = 0;    nb = t % 56; kb = t / 56; }
    else if (t < NB_TQ+NB_TK) { int u = t - NB_TQ;         W = Wk; ncols = 512; row_off = 3584; nb = u % 8; kb = u / 8; }
    else                      { int u = t - NB_TQ - NB_TK; W = Wv; ncols = 512; row_off = 4096; nb = u % 8; kb = u / 8; }

    __shared__ float tile[64][65];
    int n0 = nb * 64, k0 = kb * 64;
    int c4 = threadIdx.x & 15;          // float4 column
    int rr = threadIdx.x >> 4;          // 0..15
#pragma unroll
    for (int i = 0; i < 4; ++i) {
        int row = i * 16 + rr;
        float4 v = *(const float4*)(W + (size_t)(k0 + row) * ncols + n0 + c4 * 4);
        tile[row][c4 * 4 + 0] = v.x;
        tile[row][c4 * 4 + 1] = v.y;
        tile[row][c4 * 4 + 2] = v.z;
        tile[row][c4 * 4 + 3] = v.w;
    }
    __syncthreads();
    int kc  = threadIdx.x & 7;          // 16B k-chunk
    int nr0 = threadIdx.x >> 3;         // 0..31
#pragma unroll
    for (int cc = 0; cc < 2; ++cc) {
        int nrow = nr0 + cc * 32;
        bf16x8 o;
#pragma unroll
        for (int j = 0; j < 8; ++j) o[j] = (bf16)tile[kc * 8 + j][nrow];
        *(bf16x8*)(Bt + (size_t)(row_off + n0 + nrow) * KK + k0 + kc * 8) = o;
    }
}

// ----------------------------------------------------------------- GEMM -----
__device__ __forceinline__ void g2l16(const void* g, void* l) {
    __builtin_amdgcn_global_load_lds(
        (const __attribute__((address_space(1))) void*)g,
        (__attribute__((address_space(3))) void*)l, 16, 0, 0);
}

// AITER-shaped K-loop: per K-tile issue stage(t+2) -> counted vmcnt(12) ->
// barrier -> 32 MFMA (ds_read swizzled) -> lgkmcnt(0) -> barrier.
// 3-stage LDS: stage(t+2) writes the buffer last read at tile t-1 (fenced).
__global__ __launch_bounds__(512, 2) void qkv_gemm(
    const bf16* __restrict__ A, const bf16* __restrict__ Bt,
    const float* __restrict__ bq, const float* __restrict__ bk,
    const float* __restrict__ bv, const float* __restrict__ cosp,
    const float* __restrict__ sinp, float* __restrict__ out) {

    __shared__ __align__(16) bf16 As[3][BM * BK];   // 3 x 32 KB
    __shared__ __align__(16) bf16 Bs[3][BN * BK];   // 3 x 16 KB  (total 144 KB)

    const int tid  = threadIdx.x;
    const int lane = tid & 63;
    const int wave = tid >> 6;          // 0..7
    const int wm   = wave >> 1;         // 0..3: rows wm*64..+63
    const int wn   = wave & 1;          // 32-col slice pair within the head

    // bijective XCD swizzle (GRID_GEMM % 8 == 0)
    const int wg = (blockIdx.x & 7) * (GRID_GEMM / 8) + (blockIdx.x >> 3);
    const int bm = wg / NBN2;
    const int bn = wg % NBN2;
    const int m0 = bm * BM;
    const int n0 = bn * BN;             // block owns exactly one head (128 cols)

    // ---- staging: linear LDS dest (tid*16B), source k-chunk XOR-swizzled by row&7
    const int srow   = tid >> 3;                   // 0..63 (row within 64-row slab)
    const int schunk = (tid & 7) ^ (srow & 7);     // pre-swizzled global 16B chunk
    const bf16* aP = A  + (size_t)(m0 + srow) * KK + schunk * 8;
    const bf16* bP = Bt + (size_t)(n0 + srow) * KK + schunk * 8;

    auto STAGE_A = [&](int buf, const bf16* a) {
        bf16* da = &As[buf][0] + tid * 8;
#pragma unroll
        for (int i = 0; i < 4; ++i)
            g2l16(a + (size_t)(i * 64) * KK, da + i * 4096);
    };
    auto STAGE_B = [&](int buf, const bf16* b) {
        bf16* db = &Bs[buf][0] + tid * 8;
#pragma unroll
        for (int i = 0; i < 2; ++i)
            g2l16(b + (size_t)(i * 64) * KK, db + i * 4096);
    };

    // ---- fragment byte offsets (16x16x32: m/n = lane&15, k-chunk = lane>>4)
    // chunk stored at c' = c ^ (row&7); row bases are multiples of 16 so row&7==fr&7.
    // k32=1 <=> chunk^4 <=> byte^64.
    const int fr  = lane & 15;
    const int fq  = lane >> 4;
    const int fch = (fq ^ (fr & 7)) * 16;
    const int awb = (wm * 64 + fr) * 128 + fch;
    // RoPE-friendly cols: ni -> wn*32 + (ni>>1)*16 + (ni&1)*64
    // (byte deltas 0, 8192, 2048, 10240 hard-coded below)
    const int bwb = (wn * 32 + fr) * 128 + fch;

    floatx4 acc[4][4];
#pragma unroll
    for (int mi = 0; mi < 4; ++mi)
#pragma unroll
        for (int ni = 0; ni < 4; ++ni)
            acc[mi][ni] = (floatx4){0.f, 0.f, 0.f, 0.f};

    // prologue: stage tiles 0,1 into bufs 0,1 (no wait yet)
    const bf16* aS = aP;
    const bf16* bS = bP;
    STAGE_A(0, aS); STAGE_B(0, bS); aS += BK; bS += BK;
    STAGE_A(1, aS); STAGE_B(1, bS); aS += BK; bS += BK;

    int cb = 0, sb = 2;
    for (int t = 0; t < NKT; ++t) {
        if (t + 2 < NKT) {
            STAGE_A(sb, aS); STAGE_B(sb, bS);
            aS += BK; bS += BK;
            asm volatile("s_waitcnt vmcnt(12)" ::: "memory");   // stage(t) landed
        } else if (t + 2 == NKT) {
            asm volatile("s_waitcnt vmcnt(6)" ::: "memory");
        } else {
            asm volatile("s_waitcnt vmcnt(0)" ::: "memory");
        }
        __builtin_amdgcn_s_barrier();

        const char* lA = (const char*)&As[cb][0];
        const char* lB = (const char*)&Bs[cb][0];
#pragma unroll
        for (int kx = 0; kx < 2; ++kx) {
            const int KX = kx * 64;
            bf16x8 af[4], bfv[4];
#pragma unroll
            for (int mi = 0; mi < 4; ++mi)
                af[mi] = *(const bf16x8*)(lA + ((awb + mi * 2048) ^ KX));
            bfv[0] = *(const bf16x8*)(lB + ((bwb +     0) ^ KX));
            bfv[1] = *(const bf16x8*)(lB + ((bwb +  8192) ^ KX));
            bfv[2] = *(const bf16x8*)(lB + ((bwb +  2048) ^ KX));
            bfv[3] = *(const bf16x8*)(lB + ((bwb + 10240) ^ KX));
            __builtin_amdgcn_s_setprio(1);
#pragma unroll
            for (int mi = 0; mi < 4; ++mi)
#pragma unroll
                for (int ni = 0; ni < 4; ++ni)
                    acc[mi][ni] = __builtin_amdgcn_mfma_f32_16x16x32_bf16(
                        af[mi], bfv[ni], acc[mi][ni], 0, 0, 0);
            __builtin_amdgcn_s_setprio(0);
        }
        // all reads of buf cb done before next iter's stage overwrites it
        asm volatile("s_waitcnt lgkmcnt(0)" ::: "memory");
        __builtin_amdgcn_s_barrier();

        sb = cb;
        cb = (cb == 2) ? 0 : cb + 1;
    }

    // ---- epilogue: bias + RoPE (register-local pairs) + permuted store -----
    const float* bias;
    int h, nh;
    size_t obase;
    bool rope;
    if (n0 < 3584)      { bias = bq + n0;          h = n0 >> 7;          obase = QOFF; nh = NHQ;  rope = true;  }
    else if (n0 < 4096) { bias = bk + (n0 - 3584); h = (n0 - 3584) >> 7; obase = KOFF; nh = NKVH; rope = true;  }
    else                { bias = bv + (n0 - 4096); h = (n0 - 4096) >> 7; obase = VOFF; nh = NKVH; rope = false; }

    float blo[2], bhi[2];
#pragma unroll
    for (int p = 0; p < 2; ++p) {
        int d = wn * 32 + p * 16 + fr;     // in [0,64)
        blo[p] = bias[d];
        bhi[p] = bias[d + 64];
    }

#pragma unroll
    for (int mi = 0; mi < 4; ++mi) {
#pragma unroll
        for (int r = 0; r < 4; ++r) {
            int m = m0 + wm * 64 + mi * 16 + fq * 4 + r;   // C/D: row=quad*4+reg
            int b = m >> 12;                                // m / S
            int s = m & 4095;                               // m % S
            size_t orow = obase + ((size_t)(b * nh + h) * SS + s) * DD;
#pragma unroll
            for (int p = 0; p < 2; ++p) {
                int d = wn * 32 + p * 16 + fr;
                float xlo = acc[mi][2 * p][r] + blo[p];
                float xhi = acc[mi][2 * p + 1][r] + bhi[p];
                float ylo, yhi;
                if (rope) {
                    float c  = cosp[(size_t)m * DD + d];
                    float sn = sinp[(size_t)m * DD + d];
                    ylo = xlo * c - xhi * sn;      // d < 64:  x*cos - x_hi*sin
                    yhi = xhi * c + xlo * sn;      // d >= 64: x*cos + x_lo*sin
                } else {
                    ylo = xlo; yhi = xhi;
                }
                out[orow + d]      = ylo;
                out[orow + d + 64] = yhi;
            }
        }
    }
}

// ---------------------------------------------------------------- launch ----
extern "C" void kernel_launch(void* const* d_in, const int* in_sizes, int n_in,
                              void* d_out, int out_size, void* d_ws, size_t ws_size,
                              hipStream_t stream) {
    const float* hs   = (const float*)d_in[0];
    const float* cosp = (const float*)d_in[1];
    const float* sinp = (const float*)d_in[2];
    const float* Wq   = (const float*)d_in[3];
    const float* bq   = (const float*)d_in[4];
    const float* Wk   = (const float*)d_in[5];
    const float* bk   = (const float*)d_in[6];
    const float* Wv   = (const float*)d_in[7];
    const float* bv   = (const float*)d_in[8];
    float* out = (float*)d_out;

    bf16* Abf = (bf16*)d_ws;                      // 8192x3584 bf16 = 58.7 MB
    bf16* Btb = Abf + (size_t)MM * KK;            // 4608x3584 bf16 = 33.0 MB

    prep<<<NB_PREP, 256, 0, stream>>>(hs, Wq, Wk, Wv, Abf, Btb);
    qkv_gemm<<<GRID_GEMM, 512, 0, stream>>>(Abf, Btb, bq, bk, bv, cosp, sinp, out);
}

// Round 3
// 641.218 us; speedup vs baseline: 1.2076x; 1.2076x over previous
//
#include <hip/hip_runtime.h>
#include <hip/hip_bf16.h>
#include <cstdint>
#include <cstddef>

// Problem constants (Qwen2: B=2,S=4096,H=3584,NH=28,NKV=4,D=128)
#define SS 4096
#define HH 3584
#define NHQ 28
#define NKVH 4
#define DD 128
#define MM 8192                 // B*S
#define NN 4608                 // (NH+2*NKV)*D
#define KK 3584
#define QOFF 0
#define KOFF 29360128ULL        // B*NH*S*D
#define VOFF 33554432ULL        // KOFF + B*NKV*S*D

// GEMM tiling: 256x256 tile, BK=64 per K-tile, 8 waves (2M x 4N), wave tile 128x64
// 8-phase schedule over 2 K-tiles per iteration (m201 template).
#define BM 256
#define BN 256
#define NIT 28                  // KK / 128  (2 K-tiles per iteration)
#define NBN3 18                 // NN/BN
#define GRID_GEMM 576           // 32*18, %8==0 -> bijective XCD swizzle
#define SLOTB 16384             // half-tile slot bytes (256 rows x 32 k x 2B)

// prep block ranges
#define NB_CVT 7168             // MM*KK/16/256
#define NB_TQ 3136              // (3584/64)*(3584/64)
#define NB_TK 448               // (512/64)*(3584/64)
#define NB_PREP (NB_CVT + NB_TQ + 2 * NB_TK)

typedef __bf16 bf16;
typedef bf16  bf16x8  __attribute__((ext_vector_type(8)));
typedef float floatx4 __attribute__((ext_vector_type(4)));

// ------------------------------------------------------------- fused prep ---
__global__ __launch_bounds__(256) void prep(
    const float* __restrict__ hs, const float* __restrict__ Wq,
    const float* __restrict__ Wk, const float* __restrict__ Wv,
    bf16* __restrict__ Abf, bf16* __restrict__ Bt) {

    int blk = blockIdx.x;
    if (blk < NB_CVT) {
        size_t i = (size_t)blk * 256 + threadIdx.x;      // 16 floats per thread
        const float4* s = (const float4*)hs;
        float4 a = s[4 * i], b = s[4 * i + 1], c = s[4 * i + 2], d = s[4 * i + 3];
        bf16x8 o0, o1;
        o0[0] = (bf16)a.x; o0[1] = (bf16)a.y; o0[2] = (bf16)a.z; o0[3] = (bf16)a.w;
        o0[4] = (bf16)b.x; o0[5] = (bf16)b.y; o0[6] = (bf16)b.z; o0[7] = (bf16)b.w;
        o1[0] = (bf16)c.x; o1[1] = (bf16)c.y; o1[2] = (bf16)c.z; o1[3] = (bf16)c.w;
        o1[4] = (bf16)d.x; o1[5] = (bf16)d.y; o1[6] = (bf16)d.z; o1[7] = (bf16)d.w;
        *(bf16x8*)(Abf + i * 16)     = o0;
        *(bf16x8*)(Abf + i * 16 + 8) = o1;
        return;
    }
    // ---- transpose part: 64x64 fp32 tile -> Bt (n,k) bf16 ----
    const float* W; int ncols, row_off, nb, kb;
    int t = blk - NB_CVT;
    if (t < NB_TQ)            { W = Wq; ncols = 3584; row_off = 0;    nb = t % 56; kb = t / 56; }
    else if (t < NB_TQ+NB_TK) { int u = t - NB_TQ;         W = Wk; ncols = 512; row_off = 3584; nb = u % 8; kb = u / 8; }
    else                      { int u = t - NB_TQ - NB_TK; W = Wv; ncols = 512; row_off = 4096; nb = u % 8; kb = u / 8; }

    __shared__ float tile[64][65];
    int n0 = nb * 64, k0 = kb * 64;
    int c4 = threadIdx.x & 15;          // float4 column
    int rr = threadIdx.x >> 4;          // 0..15
#pragma unroll
    for (int i = 0; i < 4; ++i) {
        int row = i * 16 + rr;
        float4 v = *(const float4*)(W + (size_t)(k0 + row) * ncols + n0 + c4 * 4);
        tile[row][c4 * 4 + 0] = v.x;
        tile[row][c4 * 4 + 1] = v.y;
        tile[row][c4 * 4 + 2] = v.z;
        tile[row][c4 * 4 + 3] = v.w;
    }
    __syncthreads();
    int kc  = threadIdx.x & 7;          // 16B k-chunk
    int nr0 = threadIdx.x >> 3;         // 0..31
#pragma unroll
    for (int cc = 0; cc < 2; ++cc) {
        int nrow = nr0 + cc * 32;
        bf16x8 o;
#pragma unroll
        for (int j = 0; j < 8; ++j) o[j] = (bf16)tile[kc * 8 + j][nrow];
        *(bf16x8*)(Bt + (size_t)(row_off + n0 + nrow) * KK + k0 + kc * 8) = o;
    }
}

// ----------------------------------------------------------------- GEMM -----
__device__ __forceinline__ void g2l16(const void* g, void* l) {
    __builtin_amdgcn_global_load_lds(
        (const __attribute__((address_space(1))) void*)g,
        (__attribute__((address_space(3))) void*)l, 16, 0, 0);
}

// stage one half-tile (256 rows x 32 k) into LDS slot: 2 x g2l16 per thread
#define STAGE(slot, srcB, koff) do {                                         \
    g2l16((srcB) + (koff),            lds + (slot) * 8192 + tid * 8);        \
    g2l16((srcB) + (koff) + 128 * KK, lds + (slot) * 8192 + 4096 + tid * 8); \
} while (0)

// Phase: {ds_read frags | stage 1 half-tile | opt vmcnt | barrier |
//         lgkmcnt(0) | setprio(1) 16xMFMA setprio(0) | barrier}
#define PH(ASL, BSL, MS, RELB, STG, WAITC) do {                              \
    bf16x8 af[4];                                                            \
    _Pragma("unroll")                                                        \
    for (int mi = 0; mi < 4; ++mi)                                           \
        af[mi] = *(const bf16x8*)(ldsC + (ASL) * SLOTB + aRdB + ((MS) * 4 + mi) * 1024); \
    if (RELB) {                                                              \
        bfv[0] = *(const bf16x8*)(ldsC + (BSL) * SLOTB + bRdB + 0);          \
        bfv[1] = *(const bf16x8*)(ldsC + (BSL) * SLOTB + bRdB + 4096);       \
        bfv[2] = *(const bf16x8*)(ldsC + (BSL) * SLOTB + bRdB + 1024);       \
        bfv[3] = *(const bf16x8*)(ldsC + (BSL) * SLOTB + bRdB + 5120);       \
    }                                                                        \
    STG;                                                                     \
    WAITC;                                                                   \
    __builtin_amdgcn_s_barrier();                                            \
    asm volatile("s_waitcnt lgkmcnt(0)" ::: "memory");                       \
    __builtin_amdgcn_s_setprio(1);                                           \
    _Pragma("unroll")                                                        \
    for (int mi = 0; mi < 4; ++mi)                                           \
        _Pragma("unroll")                                                    \
        for (int ni = 0; ni < 4; ++ni)                                       \
            acc[(MS) * 4 + mi][ni] = __builtin_amdgcn_mfma_f32_16x16x32_bf16( \
                af[mi], bfv[ni], acc[(MS) * 4 + mi][ni], 0, 0, 0);           \
    __builtin_amdgcn_s_setprio(0);                                           \
    __builtin_amdgcn_s_barrier();                                            \
} while (0)

__global__ __launch_bounds__(512, 2) void qkv_gemm(
    const bf16* __restrict__ A, const bf16* __restrict__ Bt,
    const float* __restrict__ bq, const float* __restrict__ bk,
    const float* __restrict__ bv, const float* __restrict__ cosp,
    const float* __restrict__ sinp, float* __restrict__ out) {

    // 8 half-tile slots x 16 KB = 128 KB:
    // s0=(A,T0,k0) s1=(B,T0,k0) s2=(A,T0,k1) s3=(B,T0,k1)
    // s4=(A,T1,k0) s5=(B,T1,k0) s6=(A,T1,k1) s7=(B,T1,k1)
    __shared__ __align__(16) bf16 lds[8 * 8192];

    const int tid  = threadIdx.x;
    const int lane = tid & 63;
    const int wave = tid >> 6;          // 0..7
    const int wm   = wave >> 2;         // M-half: rows wm*128..+127
    const int wn   = wave & 3;
    const int hh   = wn >> 1;           // head within 256-col tile (also B N-half)
    const int pw   = wn & 1;            // 32-col slice within head

    // bijective XCD swizzle (GRID_GEMM % 8 == 0)
    const int wg = (blockIdx.x & 7) * (GRID_GEMM / 8) + (blockIdx.x >> 3);
    const int bm = wg / NBN3;
    const int bn = wg % NBN3;
    const int m0 = bm * BM;
    const int n0 = bn * BN;

    // ---- staging addresses: dest linear tid*16B (row=tid>>2, chunk=tid&3),
    // source chunk XOR-swizzled: sch = (tid&3) ^ (r&3) ^ ((r>>2)&3)
    const int srow = tid >> 2;
    const int sch  = (tid & 3) ^ (srow & 3) ^ ((srow >> 2) & 3);
    const bf16* aSrc = A  + (size_t)(m0 + srow) * KK + sch * 8;
    const bf16* bSrc = Bt + (size_t)(n0 + srow) * KK + sch * 8;

    // ---- fragment read bases (16x16x32: m/n = lane&15, k-chunk = lane>>4)
    // LDS slot layout: [256 rows][4 chunks of 16B], chunk' = fq ^ (row&3) ^ ((row>>2)&3)
    const int fr  = lane & 15;
    const int fq  = lane >> 4;
    const int fxr = (fr & 3) ^ ((fr >> 2) & 3);
    const int aRdB = (wm * 128 + fr) * 64 + ((fq ^ fxr) * 16);
    // B cols per wave: hh*128 + pw*32 + {0,+16}x{0,+64}; deltas 4096B(+64), 1024B(+16)
    const int bRdB = (hh * 128 + pw * 32 + fr) * 64 + ((fq ^ fxr) * 16);
    const char* ldsC = (const char*)lds;

    floatx4 acc[8][4];
#pragma unroll
    for (int mi = 0; mi < 8; ++mi)
#pragma unroll
        for (int ni = 0; ni < 4; ++ni)
            acc[mi][ni] = (floatx4){0.f, 0.f, 0.f, 0.f};
    bf16x8 bfv[4] = {};

    // ---- prologue: stage slots 0-5 (tile0 k0/k1, tile1 k0), land 0-3
    STAGE(0, aSrc, 0);
    STAGE(1, bSrc, 0);
    STAGE(2, aSrc, 32);
    STAGE(3, bSrc, 32);
    STAGE(4, aSrc, 64);
    STAGE(5, bSrc, 64);
    asm volatile("s_waitcnt vmcnt(4)" ::: "memory");
    __builtin_amdgcn_s_barrier();

    for (int j = 0; j < NIT; ++j) {
        const bool st = (j < NIT - 1);
        const int t1k1 = (2 * j + 1) * 64 + 32;    // (T1, k1)
        const int n0k0 = (2 * j + 2) * 64;         // (next T0, k0)
        const int n0k1 = n0k0 + 32;                // (next T0, k1)
        const int n1k0 = (2 * j + 3) * 64;         // (next T1, k0)

        // P1..P8: reads (slot pair, msub) | stage schedule (6-phase lead)
        PH(0, 1, 0, 1, STAGE(6, aSrc, t1k1), );
        PH(0, 1, 1, 0, STAGE(7, bSrc, t1k1), );
        PH(2, 3, 0, 1, if (st) STAGE(0, aSrc, n0k0), );
        PH(2, 3, 1, 0, if (st) STAGE(1, bSrc, n0k0),
           if (st) { asm volatile("s_waitcnt vmcnt(4)" ::: "memory"); }
           else    { asm volatile("s_waitcnt vmcnt(0)" ::: "memory"); });
        PH(4, 5, 0, 1, if (st) STAGE(2, aSrc, n0k1), );
        PH(4, 5, 1, 0, if (st) STAGE(3, bSrc, n0k1), );
        PH(6, 7, 0, 1, if (st) STAGE(4, aSrc, n1k0), );
        PH(6, 7, 1, 0, if (st) STAGE(5, bSrc, n1k0),
           if (st) { asm volatile("s_waitcnt vmcnt(4)" ::: "memory"); });
    }

    // ---- epilogue: bias + RoPE (register-local pairs) + permuted store -----
    const float* bias;
    int hbase, nh;
    size_t obase;
    bool rope;
    if (n0 < 3584)      { bias = bq + n0;          hbase = n0 >> 7;          obase = QOFF; nh = NHQ;  rope = true;  }
    else if (n0 < 4096) { bias = bk + (n0 - 3584); hbase = (n0 - 3584) >> 7; obase = KOFF; nh = NKVH; rope = true;  }
    else                { bias = bv + (n0 - 4096); hbase = (n0 - 4096) >> 7; obase = VOFF; nh = NKVH; rope = false; }
    const int h = hbase + hh;

    float blo[2], bhi[2];
#pragma unroll
    for (int p = 0; p < 2; ++p) {
        int d = pw * 32 + p * 16 + fr;     // in [0,64)
        blo[p] = bias[hh * 128 + d];
        bhi[p] = bias[hh * 128 + d + 64];
    }

#pragma unroll
    for (int mi = 0; mi < 8; ++mi) {
#pragma unroll
        for (int r = 0; r < 4; ++r) {
            int m = m0 + wm * 128 + mi * 16 + fq * 4 + r;   // C/D: row=quad*4+reg
            int b = m >> 12;                                // m / S
            int s = m & 4095;                               // m % S
            size_t orow = obase + ((size_t)(b * nh + h) * SS + s) * DD;
#pragma unroll
            for (int p = 0; p < 2; ++p) {
                int d = pw * 32 + p * 16 + fr;
                float xlo = acc[mi][2 * p][r] + blo[p];
                float xhi = acc[mi][2 * p + 1][r] + bhi[p];
                float ylo, yhi;
                if (rope) {
                    float c  = cosp[(size_t)m * DD + d];
                    float sn = sinp[(size_t)m * DD + d];
                    ylo = xlo * c - xhi * sn;      // d < 64:  x*cos - x_hi*sin
                    yhi = xhi * c + xlo * sn;      // d >= 64: x*cos + x_lo*sin
                } else {
                    ylo = xlo; yhi = xhi;
                }
                out[orow + d]      = ylo;
                out[orow + d + 64] = yhi;
            }
        }
    }
}

// ---------------------------------------------------------------- launch ----
extern "C" void kernel_launch(void* const* d_in, const int* in_sizes, int n_in,
                              void* d_out, int out_size, void* d_ws, size_t ws_size,
                              hipStream_t stream) {
    const float* hs   = (const float*)d_in[0];
    const float* cosp = (const float*)d_in[1];
    const float* sinp = (const float*)d_in[2];
    const float* Wq   = (const float*)d_in[3];
    const float* bq   = (const float*)d_in[4];
    const float* Wk   = (const float*)d_in[5];
    const float* bk   = (const float*)d_in[6];
    const float* Wv   = (const float*)d_in[7];
    const float* bv   = (const float*)d_in[8];
    float* out = (float*)d_out;

    bf16* Abf = (bf16*)d_ws;                      // 8192x3584 bf16 = 58.7 MB
    bf16* Btb = Abf + (size_t)MM * KK;            // 4608x3584 bf16 = 33.0 MB

    prep<<<NB_PREP, 256, 0, stream>>>(hs, Wq, Wk, Wv, Abf, Btb);
    qkv_gemm<<<GRID_GEMM, 512, 0, stream>>>(Abf, Btb, bq, bk, bv, cosp, sinp, out);
}